// Round 3
// baseline (1727.767 us; speedup 1.0000x reference)
//
#include <hip/hip_runtime.h>
#include <hip/hip_bf16.h>

// All device buffers are float32 (comparison is vs bf16-cast reference, 2% thr).

#define NTOK 49
#define CDIM 96
#define SCALE_QK 0.17677669529663687f  // 32^-0.5

// ============================================================================
// Fused: shift -> qkv -> window attention (bias+mask+softmax) -> PV -> W_out
//        projection -> un-shift -> write f32 out.
// One block per (batch, window). 192 threads = 3 waves.
// ============================================================================
__global__ __launch_bounds__(192) void swin_attn_kernel(
    const float* __restrict__ x,
    const float* __restrict__ w_qkv,   // [96][288]
    const float* __restrict__ pos_emb, // [13][13]
    const float* __restrict__ w_out,   // [96][96]
    const float* __restrict__ b_out,   // [96]
    float* __restrict__ out)           // [8][224][224][96]
{
    __shared__ float x_tile[NTOK][CDIM];   // 18816 B
    __shared__ float q_s[NTOK][32];        // 6272 B (reused as attn-out per head)
    __shared__ float kT_s[32][NTOK];       // 6272 B
    __shared__ float v_s[NTOK][32];        // 6272 B
    __shared__ float dots_s[NTOK][NTOK];   // 9604 B
    __shared__ float pos_s[169];           // 676 B

    const int blk = blockIdx.x;            // 0..8191
    const int b   = blk >> 10;
    const int win = blk & 1023;
    const int wh  = win >> 5;              // window row 0..31
    const int ww  = win & 31;              // window col 0..31
    const int tid = threadIdx.x;
    const bool mUL = (wh == 31);
    const bool mLR = (ww == 31);

    for (int i = tid; i < 169; i += 192) pos_s[i] = pos_emb[i];

    // load shifted x tile: token i at shifted coords (wh*7+i/7, ww*7+i%7)
    // comes from x[(row+3)%224][(col+3)%224]
    for (int idx = tid; idx < NTOK * CDIM; idx += 192) {
        int i = idx / CDIM, c = idx - i * CDIM;
        int sr = wh * 7 + i / 7 + 3;  if (sr >= 224) sr -= 224;
        int sc = ww * 7 + (i % 7) + 3; if (sc >= 224) sc -= 224;
        x_tile[i][c] = x[(((size_t)b * 224 + sr) * 224 + sc) * CDIM + c];
    }

    const int combo = tid % CDIM;   // 0..95
    const int half  = tid / CDIM;   // 0..1
    const int tok0  = half ? 25 : 0;
    const int ntok  = half ? 24 : 25;
    const int sel   = combo >> 5;   // 0=q, 1=k, 2=v
    const int d     = combo & 31;

    float accp[25];                 // projection accumulators: token x out-channel(=combo)
    #pragma unroll
    for (int t = 0; t < 25; ++t) accp[t] = 0.f;

    for (int h = 0; h < 3; ++h) {
        __syncthreads();  // x ready (h=0) / previous head's proj reads done

        // ---- phase 1: qkv for head h (thread computes one column over tokens) ----
        float acc[25];
        #pragma unroll
        for (int t = 0; t < 25; ++t) acc[t] = 0.f;
        const int col = sel * CDIM + h * 32 + d;
        for (int ch = 0; ch < CDIM; ++ch) {
            float w = w_qkv[ch * 288 + col];
            #pragma unroll
            for (int t = 0; t < 25; ++t)
                if (t < ntok) acc[t] = fmaf(x_tile[tok0 + t][ch], w, acc[t]);
        }
        #pragma unroll
        for (int t = 0; t < 25; ++t) if (t < ntok) {
            int tok = tok0 + t;
            if (sel == 0)      q_s[tok][d]  = acc[t];
            else if (sel == 1) kT_s[d][tok] = acc[t];
            else               v_s[tok][d]  = acc[t];
        }
        __syncthreads();

        // ---- phase 2: dots = q k^T * scale + bias (+ boundary masks) ----
        for (int e = tid; e < NTOK * NTOK; e += 192) {
            int i = e / NTOK, j = e - i * NTOK;
            float s = 0.f;
            #pragma unroll
            for (int dd = 0; dd < 32; ++dd) s = fmaf(q_s[i][dd], kT_s[dd][j], s);
            int ir = i / 7, ic2 = i - ir * 7, jr = j / 7, jc = j - jr * 7;
            float val = s * SCALE_QK + pos_s[(jr - ir + 6) * 13 + (jc - ic2 + 6)];
            if (mUL && ((ir  >= 4) != (jr >= 4))) val = -1e30f;
            if (mLR && ((ic2 >= 4) != (jc >= 4))) val = -1e30f;
            dots_s[i][j] = val;
        }
        __syncthreads();

        // ---- phase 3: softmax rows (49 threads, one row each) ----
        if (tid < NTOK) {
            float m = -1e30f;
            for (int j = 0; j < NTOK; ++j) m = fmaxf(m, dots_s[tid][j]);
            float ssum = 0.f;
            for (int j = 0; j < NTOK; ++j) {
                float e2 = __expf(dots_s[tid][j] - m);
                dots_s[tid][j] = e2; ssum += e2;
            }
            float inv = 1.f / ssum;
            for (int j = 0; j < NTOK; ++j) dots_s[tid][j] *= inv;
        }
        __syncthreads();

        // ---- phase 4: PV -> per-head output (into q_s) ----
        for (int e = tid; e < NTOK * 32; e += 192) {
            int i = e >> 5, dd = e & 31;
            float s = 0.f;
            #pragma unroll
            for (int j = 0; j < NTOK; ++j) s = fmaf(dots_s[i][j], v_s[j][dd], s);
            q_s[i][dd] = s;
        }
        __syncthreads();

        // ---- phase 5: accumulate output projection (head slice of W_out) ----
        for (int dd = 0; dd < 32; ++dd) {
            float w = w_out[(h * 32 + dd) * CDIM + combo];
            #pragma unroll
            for (int t = 0; t < 25; ++t)
                if (t < ntok) accp[t] = fmaf(q_s[tok0 + t][dd], w, accp[t]);
        }
    }

    // ---- write with roll-back (+3,+3): same coords as the x element we read ----
    const float bo = b_out[combo];
    #pragma unroll
    for (int t = 0; t < 25; ++t) if (t < ntok) {
        int tok = tok0 + t;
        int sr = wh * 7 + tok / 7 + 3;  if (sr >= 224) sr -= 224;
        int sc = ww * 7 + (tok % 7) + 3; if (sc >= 224) sc -= 224;
        out[(((size_t)b * 224 + sr) * 224 + sc) * CDIM + combo] = accp[t] + bo;
    }
}

// ============================================================================
// Stage 1 spatial reduction: per (b, chunk) partial sum & max over channels.
// grid (64 chunks, 8 batch), 192 threads: c = tid%96, sub = tid/96.
// ============================================================================
__global__ __launch_bounds__(192) void reduce_kernel(
    const float* __restrict__ out,
    float* __restrict__ psum, float* __restrict__ pmax)
{
    const int chunk = blockIdx.x;     // 0..63, 784 positions each
    const int b     = blockIdx.y;
    const int c     = threadIdx.x % 96;
    const int sub   = threadIdx.x / 96;
    const int p0    = chunk * 784 + sub * 392;
    const float* base = out + (size_t)b * 50176 * 96;

    float s = 0.f, m = -1e30f;
    for (int k = 0; k < 392; ++k) {
        float v = base[(size_t)(p0 + k) * 96 + c];
        s += v; m = fmaxf(m, v);
    }
    __shared__ float ls[192], lm[192];
    ls[threadIdx.x] = s; lm[threadIdx.x] = m;
    __syncthreads();
    if (sub == 0) {
        psum[((size_t)b * 64 + chunk) * 96 + c] = ls[c] + ls[96 + c];
        pmax[((size_t)b * 64 + chunk) * 96 + c] = fmaxf(lm[c], lm[96 + c]);
    }
}

// ============================================================================
// Stage 2: finish avg/max, run both MLPs, sigmoid gate. One block per batch.
// ============================================================================
__global__ __launch_bounds__(128) void gate_kernel(
    const float* __restrict__ psum, const float* __restrict__ pmax,
    const float* __restrict__ w11, const float* __restrict__ b11,
    const float* __restrict__ w12, const float* __restrict__ b12,
    const float* __restrict__ w21, const float* __restrict__ b21,
    const float* __restrict__ w22, const float* __restrict__ b22,
    float* __restrict__ gate)
{
    const int b = blockIdx.x;
    const int c = threadIdx.x;
    __shared__ float avg[96], mx[96], h1[96], h2[96];
    if (c < 96) {
        float s = 0.f, m = -1e30f;
        for (int k = 0; k < 64; ++k) {
            s += psum[((size_t)b * 64 + k) * 96 + c];
            m = fmaxf(m, pmax[((size_t)b * 64 + k) * 96 + c]);
        }
        avg[c] = s * (1.0f / 50176.0f);
        mx[c]  = m;
    }
    __syncthreads();
    if (c < 96) {
        float sa = b11[c], sm = b21[c];
        for (int ic = 0; ic < 96; ++ic) {
            sa = fmaf(avg[ic], w11[ic * 96 + c], sa);
            sm = fmaf(mx[ic],  w21[ic * 96 + c], sm);
        }
        h1[c] = fmaxf(sa, 0.f);
        h2[c] = fmaxf(sm, 0.f);
    }
    __syncthreads();
    if (c < 96) {
        float a = b12[c], m2 = b22[c];
        for (int hh = 0; hh < 96; ++hh) {
            a  = fmaf(h1[hh], w12[hh * 96 + c], a);
            m2 = fmaf(h2[hh], w22[hh * 96 + c], m2);
        }
        float g = a + m2;
        gate[b * 96 + c] = 1.0f / (1.0f + __expf(-g));
    }
}

// ============================================================================
// Final: out[b,h,w,c] *= gate[b,c]   (in place, f32, float4)
// ============================================================================
__global__ __launch_bounds__(256) void scale_kernel(
    float* __restrict__ out, const float* __restrict__ gate)
{
    const size_t total4 = 38535168u / 4;   // 9,633,792
    for (size_t i4 = (size_t)blockIdx.x * blockDim.x + threadIdx.x; i4 < total4;
         i4 += (size_t)gridDim.x * blockDim.x) {
        size_t base = i4 * 4;
        int c = (int)(base % 96);
        int b = (int)(base / ((size_t)50176 * 96));
        float4 u = ((const float4*)out)[i4];
        float4 g = *(const float4*)(gate + b * 96 + c);
        float4 o;
        o.x = u.x * g.x;
        o.y = u.y * g.y;
        o.z = u.z * g.z;
        o.w = u.w * g.w;
        ((float4*)out)[i4] = o;
    }
}

extern "C" void kernel_launch(void* const* d_in, const int* in_sizes, int n_in,
                              void* d_out, int out_size, void* d_ws, size_t ws_size,
                              hipStream_t stream) {
    const float* x     = (const float*)d_in[0];
    const float* wqkv  = (const float*)d_in[1];
    const float* pos   = (const float*)d_in[2];
    const float* wout  = (const float*)d_in[3];
    const float* bout  = (const float*)d_in[4];
    const float* m1w1  = (const float*)d_in[5];
    const float* m1b1  = (const float*)d_in[6];
    const float* m1w2  = (const float*)d_in[7];
    const float* m1b2  = (const float*)d_in[8];
    const float* m2w1  = (const float*)d_in[9];
    const float* m2b1  = (const float*)d_in[10];
    const float* m2w2  = (const float*)d_in[11];
    const float* m2b2  = (const float*)d_in[12];
    float* out = (float*)d_out;

    float* psum = (float*)d_ws;            // 8*64*96 f32
    float* pmax = psum + 8 * 64 * 96;      // 8*64*96 f32
    float* gate = pmax + 8 * 64 * 96;      // 8*96 f32

    hipLaunchKernelGGL(swin_attn_kernel, dim3(8192), dim3(192), 0, stream,
                       x, wqkv, pos, wout, bout, out);
    hipLaunchKernelGGL(reduce_kernel, dim3(64, 8), dim3(192), 0, stream,
                       out, psum, pmax);
    hipLaunchKernelGGL(gate_kernel, dim3(8), dim3(128), 0, stream,
                       psum, pmax, m1w1, m1b1, m1w2, m1b2,
                       m2w1, m2b1, m2w2, m2b2, gate);
    hipLaunchKernelGGL(scale_kernel, dim3(2048), dim3(256), 0, stream,
                       out, gate);
}

// Round 4
// 331.578 us; speedup vs baseline: 5.2107x; 5.2107x over previous
//
#include <hip/hip_runtime.h>
#include <hip/hip_bf16.h>

typedef __attribute__((ext_vector_type(8))) __bf16 bf16x8;
typedef __attribute__((ext_vector_type(4))) float f32x4;
typedef unsigned short u16;
typedef unsigned long long u64;

#define SCALE_QK 0.17677669529663687f  // 32^-0.5

static __device__ __forceinline__ u16 f2bu(float f) {
    union { __hip_bfloat16 h; u16 s; } z; z.h = __float2bfloat16(f); return z.s;
}
static __device__ __forceinline__ f32x4 mfma16(bf16x8 a, bf16x8 b, f32x4 c) {
    return __builtin_amdgcn_mfma_f32_16x16x32_bf16(a, b, c, 0, 0, 0);
}
static __device__ __forceinline__ bf16x8 ldfrag(const u16* p) {
    return *(const bf16x8*)p;
}

// ============================================================================
// Prep: swizzle w_qkv / w_out into MFMA B-fragment order (bf16) in workspace.
// wsq[((h*6+nt)*3+ks)*512 + l*8 + e] = wqkv[(ks*32+(l>>4)*8+e)][colmap(h,nt,l&15)]
// wso[(h*6+nt)*512 + l*8 + e]        = wout[(h*32+(l>>4)*8+e)][nt*16+(l&15)]
// ============================================================================
__global__ __launch_bounds__(256) void prep_weights(
    const float* __restrict__ w_qkv, const float* __restrict__ w_out,
    u16* __restrict__ wsq, u16* __restrict__ wso)
{
    int idx = blockIdx.x * 256 + threadIdx.x;
    if (idx < 27648) {
        int e = idx & 7, lA = (idx >> 3) & 63;
        int rest = idx >> 9;              // h*18 + nt*3 + ks
        int ks = rest % 3, nt = (rest / 3) % 6, h = rest / 18;
        int krow = ks * 32 + (lA >> 4) * 8 + e;
        int n = lA & 15;
        int gcol;
        if (nt < 2)      gcol = h * 32 + nt * 16 + n;            // q cols
        else if (nt < 4) gcol = 96 + h * 32 + (nt - 2) * 16 + n; // k cols
        else             gcol = 192 + h * 32 + (nt - 4) * 16 + n;// v cols
        wsq[idx] = f2bu(w_qkv[krow * 288 + gcol]);
    }
    if (idx < 9216) {
        int e = idx & 7, lA = (idx >> 3) & 63;
        int rest = idx >> 9;              // h*6 + nt
        int nt = rest % 6, h = rest / 6;
        int krow = h * 32 + (lA >> 4) * 8 + e;
        wso[idx] = f2bu(w_out[krow * 96 + nt * 16 + (lA & 15)]);
    }
}

// ============================================================================
// Fused MFMA swin block. One block per (batch, window); 256 threads = 4 waves.
// Wave w owns token rows 16w..16w+15 in every stage.
// LDS: x[64][104] | {Q[64][40],K[64][40]} aliased with P[64][72] | V^T[32][72]
//      | O_h[64][40] | pos[169]  = ~34 KB -> 4 blocks/CU.
// ============================================================================
__global__ __launch_bounds__(256, 4) void swin_attn_mfma(
    const float* __restrict__ x,
    const float* __restrict__ pos_emb,
    const u16*  __restrict__ wsq,
    const u16*  __restrict__ wso,
    const float* __restrict__ b_out,
    float* __restrict__ out)
{
    __shared__ __attribute__((aligned(16))) u16 x_s[64 * 104];
    __shared__ __attribute__((aligned(16))) u16 qkp_s[5120];   // Q|K or P
    __shared__ __attribute__((aligned(16))) u16 vT_s[32 * 72];
    __shared__ __attribute__((aligned(16))) u16 o_s[64 * 40];
    __shared__ float pos_f[169];

    const int blk = blockIdx.x;
    const int b = blk >> 10, win = blk & 1023;
    const int wh = win >> 5, ww = win & 31;
    const int tid = threadIdx.x;
    const int w = tid >> 6, l = tid & 63, lr = l & 15, lg = l >> 4;

    // ---- load shifted x tile (rows 0..48), zero rows 49..63, load pos ----
    for (int idx = tid; idx < 49 * 24; idx += 256) {
        int t = idx / 24, c4 = idx - t * 24;
        int sr = wh * 7 + t / 7 + 3;  if (sr >= 224) sr -= 224;
        int sc = ww * 7 + t % 7 + 3;  if (sc >= 224) sc -= 224;
        const float4 v = *(const float4*)(x + (((size_t)b * 224 + sr) * 224 + sc) * 96 + c4 * 4);
        u64 pk = (u64)f2bu(v.x) | ((u64)f2bu(v.y) << 16) |
                 ((u64)f2bu(v.z) << 32) | ((u64)f2bu(v.w) << 48);
        *(u64*)&x_s[t * 104 + c4 * 4] = pk;
    }
    for (int idx = tid; idx < 15 * 24; idx += 256) {
        int t = 49 + idx / 24, c4 = idx % 24;
        *(u64*)&x_s[t * 104 + c4 * 4] = 0ull;
    }
    for (int i2 = tid; i2 < 169; i2 += 256) pos_f[i2] = pos_emb[i2];
    __syncthreads();

    // ---- per-lane bias/mask table for its 16 S elements (head-invariant) ----
    float bias[4][4];
    {
        const bool mUL = (wh == 31), mLR = (ww == 31);
        #pragma unroll
        for (int reg = 0; reg < 4; ++reg) {
            int i = 16 * w + lg * 4 + reg;
            int ir = i / 7, ic = i - ir * 7;
            #pragma unroll
            for (int nt = 0; nt < 4; ++nt) {
                int j = nt * 16 + lr;
                float v;
                if (j >= 49) v = -1e30f;
                else if (i >= 49) v = 0.f;
                else {
                    int jr = j / 7, jc = j - jr * 7;
                    v = pos_f[(jr - ir + 6) * 13 + (jc - ic + 6)];
                    if (mUL && ((ir >= 4) != (jr >= 4))) v = -1e30f;
                    if (mLR && ((ic >= 4) != (jc >= 4))) v = -1e30f;
                }
                bias[reg][nt] = v;
            }
        }
    }

    f32x4 proj[6];
    #pragma unroll
    for (int nt = 0; nt < 6; ++nt) proj[nt] = (f32x4){0.f, 0.f, 0.f, 0.f};

    for (int h = 0; h < 3; ++h) {
        __syncthreads();   // B1: prev head's P/V^T/O reads all done

        // ---- GEMM1: QKV head h = X[64x96] @ Wqkv_h -> write Q,K,V^T ----
        bf16x8 ax0 = ldfrag(&x_s[(16 * w + lr) * 104 +  0 + lg * 8]);
        bf16x8 ax1 = ldfrag(&x_s[(16 * w + lr) * 104 + 32 + lg * 8]);
        bf16x8 ax2 = ldfrag(&x_s[(16 * w + lr) * 104 + 64 + lg * 8]);
        #pragma unroll
        for (int nt = 0; nt < 6; ++nt) {
            const u16* wb = wsq + ((size_t)(h * 6 + nt) * 3 * 64 + l) * 8;
            f32x4 c = {0.f, 0.f, 0.f, 0.f};
            c = mfma16(ax0, ldfrag(wb), c);
            c = mfma16(ax1, ldfrag(wb + 512), c);
            c = mfma16(ax2, ldfrag(wb + 1024), c);
            if (nt < 2) {
                #pragma unroll
                for (int reg = 0; reg < 4; ++reg)
                    qkp_s[(16 * w + lg * 4 + reg) * 40 + nt * 16 + lr] = f2bu(c[reg] * SCALE_QK);
            } else if (nt < 4) {
                #pragma unroll
                for (int reg = 0; reg < 4; ++reg)
                    qkp_s[2560 + (16 * w + lg * 4 + reg) * 40 + (nt - 2) * 16 + lr] = f2bu(c[reg]);
            } else {
                u64 pk = (u64)f2bu(c[0]) | ((u64)f2bu(c[1]) << 16) |
                         ((u64)f2bu(c[2]) << 32) | ((u64)f2bu(c[3]) << 48);
                *(u64*)&vT_s[((nt - 4) * 16 + lr) * 72 + 16 * w + lg * 4] = pk;
            }
        }
        __syncthreads();   // B2: Q,K,V^T visible

        // ---- GEMM2: S = (Q*scale) @ K^T  (K=32, one k-step) ----
        bf16x8 aq = ldfrag(&qkp_s[(16 * w + lr) * 40 + lg * 8]);
        f32x4 S[4];
        #pragma unroll
        for (int nt = 0; nt < 4; ++nt) {
            bf16x8 bk = ldfrag(&qkp_s[2560 + (nt * 16 + lr) * 40 + lg * 8]);
            f32x4 z = {0.f, 0.f, 0.f, 0.f};
            S[nt] = mfma16(aq, bk, z);
        }

        __syncthreads();   // B3: all Q/K reads done (P aliases them)

        // ---- softmax (in-register; fixed-shift exp is exact) + P write ----
        #pragma unroll
        for (int reg = 0; reg < 4; ++reg) {
            float e[4], ssum = 0.f;
            #pragma unroll
            for (int nt = 0; nt < 4; ++nt) {
                float s = S[nt][reg] + bias[reg][nt];
                e[nt] = __expf(fminf(s, 60.f));
                ssum += e[nt];
            }
            ssum += __shfl_xor(ssum, 1);
            ssum += __shfl_xor(ssum, 2);
            ssum += __shfl_xor(ssum, 4);
            ssum += __shfl_xor(ssum, 8);
            float inv = 1.f / ssum;
            int r = 16 * w + lg * 4 + reg;
            #pragma unroll
            for (int nt = 0; nt < 4; ++nt)
                qkp_s[r * 72 + nt * 16 + lr] = f2bu(e[nt] * inv);
        }
        __syncthreads();   // B4: P visible

        // ---- GEMM3: O_h = P[64x64] @ V[64x32] ----
        bf16x8 ap0 = ldfrag(&qkp_s[(16 * w + lr) * 72 +  0 + lg * 8]);
        bf16x8 ap1 = ldfrag(&qkp_s[(16 * w + lr) * 72 + 32 + lg * 8]);
        #pragma unroll
        for (int nt = 0; nt < 2; ++nt) {
            f32x4 c = {0.f, 0.f, 0.f, 0.f};
            c = mfma16(ap0, ldfrag(&vT_s[(nt * 16 + lr) * 72 +  0 + lg * 8]), c);
            c = mfma16(ap1, ldfrag(&vT_s[(nt * 16 + lr) * 72 + 32 + lg * 8]), c);
            #pragma unroll
            for (int reg = 0; reg < 4; ++reg)
                o_s[(16 * w + lg * 4 + reg) * 40 + nt * 16 + lr] = f2bu(c[reg]);
        }
        __syncthreads();   // B5: O_h visible

        // ---- GEMM4: proj += O_h[64x32] @ Wout[h*32..][96] ----
        bf16x8 ao = ldfrag(&o_s[(16 * w + lr) * 40 + lg * 8]);
        #pragma unroll
        for (int nt = 0; nt < 6; ++nt) {
            const u16* wb = wso + ((size_t)(h * 6 + nt) * 64 + l) * 8;
            proj[nt] = mfma16(ao, ldfrag(wb), proj[nt]);
        }
    }

    // ---- epilogue: + b_out, write with roll-back (+3,+3) ----
    #pragma unroll
    for (int nt = 0; nt < 6; ++nt) {
        int c = nt * 16 + lr;
        float bo = b_out[c];
        #pragma unroll
        for (int reg = 0; reg < 4; ++reg) {
            int tok = 16 * w + lg * 4 + reg;
            if (tok < 49) {
                int sr = wh * 7 + tok / 7 + 3;  if (sr >= 224) sr -= 224;
                int sc = ww * 7 + tok % 7 + 3;  if (sc >= 224) sc -= 224;
                out[(((size_t)b * 224 + sr) * 224 + sc) * 96 + c] = proj[nt][reg] + bo;
            }
        }
    }
}

// ============================================================================
// Stage 1 spatial reduction (unchanged from passing round).
// ============================================================================
__global__ __launch_bounds__(192) void reduce_kernel(
    const float* __restrict__ out,
    float* __restrict__ psum, float* __restrict__ pmax)
{
    const int chunk = blockIdx.x;
    const int b     = blockIdx.y;
    const int c     = threadIdx.x % 96;
    const int sub   = threadIdx.x / 96;
    const int p0    = chunk * 784 + sub * 392;
    const float* base = out + (size_t)b * 50176 * 96;

    float s = 0.f, m = -1e30f;
    for (int k = 0; k < 392; ++k) {
        float v = base[(size_t)(p0 + k) * 96 + c];
        s += v; m = fmaxf(m, v);
    }
    __shared__ float ls[192], lm[192];
    ls[threadIdx.x] = s; lm[threadIdx.x] = m;
    __syncthreads();
    if (sub == 0) {
        psum[((size_t)b * 64 + chunk) * 96 + c] = ls[c] + ls[96 + c];
        pmax[((size_t)b * 64 + chunk) * 96 + c] = fmaxf(lm[c], lm[96 + c]);
    }
}

__global__ __launch_bounds__(128) void gate_kernel(
    const float* __restrict__ psum, const float* __restrict__ pmax,
    const float* __restrict__ w11, const float* __restrict__ b11,
    const float* __restrict__ w12, const float* __restrict__ b12,
    const float* __restrict__ w21, const float* __restrict__ b21,
    const float* __restrict__ w22, const float* __restrict__ b22,
    float* __restrict__ gate)
{
    const int b = blockIdx.x;
    const int c = threadIdx.x;
    __shared__ float avg[96], mx[96], h1[96], h2[96];
    if (c < 96) {
        float s = 0.f, m = -1e30f;
        for (int k = 0; k < 64; ++k) {
            s += psum[((size_t)b * 64 + k) * 96 + c];
            m = fmaxf(m, pmax[((size_t)b * 64 + k) * 96 + c]);
        }
        avg[c] = s * (1.0f / 50176.0f);
        mx[c]  = m;
    }
    __syncthreads();
    if (c < 96) {
        float sa = b11[c], sm = b21[c];
        for (int ic = 0; ic < 96; ++ic) {
            sa = fmaf(avg[ic], w11[ic * 96 + c], sa);
            sm = fmaf(mx[ic],  w21[ic * 96 + c], sm);
        }
        h1[c] = fmaxf(sa, 0.f);
        h2[c] = fmaxf(sm, 0.f);
    }
    __syncthreads();
    if (c < 96) {
        float a = b12[c], m2 = b22[c];
        for (int hh = 0; hh < 96; ++hh) {
            a  = fmaf(h1[hh], w12[hh * 96 + c], a);
            m2 = fmaf(h2[hh], w22[hh * 96 + c], m2);
        }
        float g = a + m2;
        gate[b * 96 + c] = 1.0f / (1.0f + __expf(-g));
    }
}

__global__ __launch_bounds__(256) void scale_kernel(
    float* __restrict__ out, const float* __restrict__ gate)
{
    const size_t total4 = 38535168u / 4;
    for (size_t i4 = (size_t)blockIdx.x * blockDim.x + threadIdx.x; i4 < total4;
         i4 += (size_t)gridDim.x * blockDim.x) {
        size_t base = i4 * 4;
        int c = (int)(base % 96);
        int b = (int)(base / ((size_t)50176 * 96));
        float4 u = ((const float4*)out)[i4];
        float4 g = *(const float4*)(gate + b * 96 + c);
        float4 o;
        o.x = u.x * g.x; o.y = u.y * g.y; o.z = u.z * g.z; o.w = u.w * g.w;
        ((float4*)out)[i4] = o;
    }
}

extern "C" void kernel_launch(void* const* d_in, const int* in_sizes, int n_in,
                              void* d_out, int out_size, void* d_ws, size_t ws_size,
                              hipStream_t stream) {
    const float* x     = (const float*)d_in[0];
    const float* wqkv  = (const float*)d_in[1];
    const float* pos   = (const float*)d_in[2];
    const float* wout  = (const float*)d_in[3];
    const float* bout  = (const float*)d_in[4];
    const float* m1w1  = (const float*)d_in[5];
    const float* m1b1  = (const float*)d_in[6];
    const float* m1w2  = (const float*)d_in[7];
    const float* m1b2  = (const float*)d_in[8];
    const float* m2w1  = (const float*)d_in[9];
    const float* m2b1  = (const float*)d_in[10];
    const float* m2w2  = (const float*)d_in[11];
    const float* m2b2  = (const float*)d_in[12];
    float* out = (float*)d_out;

    float* psum  = (float*)d_ws;              // 8*64*96
    float* pmax  = psum + 8 * 64 * 96;        // 8*64*96
    float* gatep = pmax + 8 * 64 * 96;        // 8*96
    u16*   wsq   = (u16*)(gatep + 8 * 96);    // 27648 bf16 (16B-aligned offset)
    u16*   wso   = wsq + 27648;               // 9216 bf16

    hipLaunchKernelGGL(prep_weights, dim3(108), dim3(256), 0, stream,
                       wqkv, wout, wsq, wso);
    hipLaunchKernelGGL(swin_attn_mfma, dim3(8192), dim3(256), 0, stream,
                       x, pos, wsq, wso, bout, out);
    hipLaunchKernelGGL(reduce_kernel, dim3(64, 8), dim3(192), 0, stream,
                       out, psum, pmax);
    hipLaunchKernelGGL(gate_kernel, dim3(8), dim3(128), 0, stream,
                       psum, pmax, m1w1, m1b1, m1w2, m1b2,
                       m2w1, m2b1, m2w2, m2b2, gatep);
    hipLaunchKernelGGL(scale_kernel, dim3(2048), dim3(256), 0, stream,
                       out, gatep);
}

// Round 5
// 310.530 us; speedup vs baseline: 5.5639x; 1.0678x over previous
//
#include <hip/hip_runtime.h>
#include <hip/hip_bf16.h>

typedef __attribute__((ext_vector_type(8))) __bf16 bf16x8;
typedef __attribute__((ext_vector_type(4))) float f32x4;
typedef unsigned short u16;
typedef unsigned long long u64;

#define SCALE_QK 0.17677669529663687f  // 32^-0.5

static __device__ __forceinline__ u16 f2bu(float f) {
    union { __hip_bfloat16 h; u16 s; } z; z.h = __float2bfloat16(f); return z.s;
}
static __device__ __forceinline__ f32x4 mfma16(bf16x8 a, bf16x8 b, f32x4 c) {
    return __builtin_amdgcn_mfma_f32_16x16x32_bf16(a, b, c, 0, 0, 0);
}
static __device__ __forceinline__ bf16x8 ldfrag(const u16* p) {
    return *(const bf16x8*)p;
}
static __device__ __forceinline__ bf16x8 zfrag() {
    union { u64 q[2]; bf16x8 v; } z; z.q[0] = 0; z.q[1] = 0; return z.v;
}
static __device__ __forceinline__ bf16x8 pack8(float4 a, float4 b) {
    union { u16 u[8]; bf16x8 v; } z;
    z.u[0] = f2bu(a.x); z.u[1] = f2bu(a.y); z.u[2] = f2bu(a.z); z.u[3] = f2bu(a.w);
    z.u[4] = f2bu(b.x); z.u[5] = f2bu(b.y); z.u[6] = f2bu(b.z); z.u[7] = f2bu(b.w);
    return z.v;
}

// ============================================================================
// Prep: swizzle w_qkv / w_out into MFMA B-fragment order (bf16) in workspace.
// ============================================================================
__global__ __launch_bounds__(256) void prep_weights(
    const float* __restrict__ w_qkv, const float* __restrict__ w_out,
    u16* __restrict__ wsq, u16* __restrict__ wso)
{
    int idx = blockIdx.x * 256 + threadIdx.x;
    if (idx < 27648) {
        int e = idx & 7, lA = (idx >> 3) & 63;
        int rest = idx >> 9;              // h*18 + nt*3 + ks
        int ks = rest % 3, nt = (rest / 3) % 6, h = rest / 18;
        int krow = ks * 32 + (lA >> 4) * 8 + e;
        int n = lA & 15;
        int gcol;
        if (nt < 2)      gcol = h * 32 + nt * 16 + n;            // q cols
        else if (nt < 4) gcol = 96 + h * 32 + (nt - 2) * 16 + n; // k cols
        else             gcol = 192 + h * 32 + (nt - 4) * 16 + n;// v cols
        wsq[idx] = f2bu(w_qkv[krow * 288 + gcol]);
    }
    if (idx < 9216) {
        int e = idx & 7, lA = (idx >> 3) & 63;
        int rest = idx >> 9;              // h*6 + nt
        int nt = rest % 6, h = rest / 6;
        int krow = h * 32 + (lA >> 4) * 8 + e;
        wso[idx] = f2bu(w_out[krow * 96 + nt * 16 + (lA & 15)]);
    }
}

// ============================================================================
// Fused MFMA swin block + per-window channel sum/max partials.
// One block per (batch, window); 256 threads = 4 waves; wave w owns token
// rows 16w..16w+15 in every stage. X fragments live in registers (global
// direct load). Only K and V^T are cross-wave -> 2 barriers per head.
// LDS ~26.5 KB -> up to 6 blocks/CU.
// ============================================================================
__global__ __launch_bounds__(256, 5) void swin_attn_mfma(
    const float* __restrict__ x,
    const float* __restrict__ pos_emb,
    const u16*  __restrict__ wsq,
    const u16*  __restrict__ wso,
    const float* __restrict__ b_out,
    float* __restrict__ out,
    float* __restrict__ psum_win,   // [8*1024][96]
    float* __restrict__ pmax_win)   // [8*1024][96]
{
    __shared__ __attribute__((aligned(16))) u16 q_s[49 * 40];   // 3920 B
    __shared__ __attribute__((aligned(16))) u16 k_s[49 * 40];   // 3920 B
    __shared__ __attribute__((aligned(16))) u16 p_s[49 * 72];   // 7056 B
    __shared__ __attribute__((aligned(16))) u16 vT_s[32 * 72];  // 4608 B
    __shared__ __attribute__((aligned(16))) u16 o_s[49 * 40];   // 3920 B
    __shared__ float rsum[4 * 96];                              // 1536 B
    __shared__ float rmax[4 * 96];                              // 1536 B

    const int blk = blockIdx.x;
    const int b = blk >> 10, win = blk & 1023;
    const int wh = win >> 5, ww = win & 31;
    const int tid = threadIdx.x;
    const int w = tid >> 6, l = tid & 63, lr = l & 15, lg = l >> 4;
    const int myrow = 16 * w + lr;        // A-fragment row this lane serves

    // ---- X A-fragments direct from global (held in registers all 3 heads) ----
    bf16x8 ax0, ax1, ax2;
    if (myrow < 49) {
        int sr = wh * 7 + myrow / 7 + 3;  if (sr >= 224) sr -= 224;
        int sc = ww * 7 + myrow % 7 + 3;  if (sc >= 224) sc -= 224;
        const float* xr = x + (((size_t)b * 224 + sr) * 224 + sc) * 96 + lg * 8;
        ax0 = pack8(*(const float4*)(xr +  0), *(const float4*)(xr +  4));
        ax1 = pack8(*(const float4*)(xr + 32), *(const float4*)(xr + 36));
        ax2 = pack8(*(const float4*)(xr + 64), *(const float4*)(xr + 68));
    } else {
        ax0 = zfrag(); ax1 = zfrag(); ax2 = zfrag();
    }

    // ---- per-lane bias/mask table for its 16 S elements (head-invariant) ----
    float bias[4][4];
    {
        const bool mUL = (wh == 31), mLR = (ww == 31);
        #pragma unroll
        for (int reg = 0; reg < 4; ++reg) {
            int i = 16 * w + lg * 4 + reg;
            int ir = i / 7, ic = i - ir * 7;
            #pragma unroll
            for (int nt = 0; nt < 4; ++nt) {
                int j = nt * 16 + lr;
                float v;
                if (j >= 49) v = -1e30f;
                else if (i >= 49) v = 0.f;
                else {
                    int jr = j / 7, jc = j - jr * 7;
                    v = pos_emb[(jr - ir + 6) * 13 + (jc - ic + 6)];
                    if (mUL && ((ir >= 4) != (jr >= 4))) v = -1e30f;
                    if (mLR && ((ic >= 4) != (jc >= 4))) v = -1e30f;
                }
                bias[reg][nt] = v;
            }
        }
    }

    f32x4 proj[6];
    #pragma unroll
    for (int nt = 0; nt < 6; ++nt) proj[nt] = (f32x4){0.f, 0.f, 0.f, 0.f};

    for (int h = 0; h < 3; ++h) {
        if (h) __syncthreads();   // B1: prev head's K/vT reads all done

        // ---- GEMM1: QKV head h -> Q (scaled), K, V^T in LDS ----
        #pragma unroll
        for (int nt = 0; nt < 6; ++nt) {
            const u16* wb = wsq + ((size_t)(h * 6 + nt) * 3 * 64 + l) * 8;
            f32x4 c = {0.f, 0.f, 0.f, 0.f};
            c = mfma16(ax0, ldfrag(wb), c);
            c = mfma16(ax1, ldfrag(wb + 512), c);
            c = mfma16(ax2, ldfrag(wb + 1024), c);
            if (nt < 2) {
                #pragma unroll
                for (int reg = 0; reg < 4; ++reg) {
                    int r = 16 * w + lg * 4 + reg;
                    if (r < 49) q_s[r * 40 + nt * 16 + lr] = f2bu(c[reg] * SCALE_QK);
                }
            } else if (nt < 4) {
                #pragma unroll
                for (int reg = 0; reg < 4; ++reg) {
                    int r = 16 * w + lg * 4 + reg;
                    if (r < 49) k_s[r * 40 + (nt - 2) * 16 + lr] = f2bu(c[reg]);
                }
            } else {
                u64 pk = (u64)f2bu(c[0]) | ((u64)f2bu(c[1]) << 16) |
                         ((u64)f2bu(c[2]) << 32) | ((u64)f2bu(c[3]) << 48);
                *(u64*)&vT_s[((nt - 4) * 16 + lr) * 72 + 16 * w + lg * 4] = pk;
            }
        }
        __syncthreads();   // B2: K, V^T visible to all waves

        // ---- GEMM2: S = (Q*scale) @ K^T (K=32, one k-step) ----
        bf16x8 aq = (myrow < 49) ? ldfrag(&q_s[myrow * 40 + lg * 8]) : zfrag();
        f32x4 S[4];
        #pragma unroll
        for (int nt = 0; nt < 4; ++nt) {
            int j = nt * 16 + lr;
            bf16x8 bk = (j < 49) ? ldfrag(&k_s[j * 40 + lg * 8]) : zfrag();
            f32x4 z = {0.f, 0.f, 0.f, 0.f};
            S[nt] = mfma16(aq, bk, z);
        }

        // ---- softmax in-register + P write (wave-private rows) ----
        #pragma unroll
        for (int reg = 0; reg < 4; ++reg) {
            float e[4], ssum = 0.f;
            #pragma unroll
            for (int nt = 0; nt < 4; ++nt) {
                float s = S[nt][reg] + bias[reg][nt];
                e[nt] = __expf(fminf(s, 60.f));
                ssum += e[nt];
            }
            ssum += __shfl_xor(ssum, 1);
            ssum += __shfl_xor(ssum, 2);
            ssum += __shfl_xor(ssum, 4);
            ssum += __shfl_xor(ssum, 8);
            float inv = 1.f / ssum;
            int r = 16 * w + lg * 4 + reg;
            if (r < 49) {
                #pragma unroll
                for (int nt = 0; nt < 4; ++nt)
                    p_s[r * 72 + nt * 16 + lr] = f2bu(e[nt] * inv);
            }
        }

        // ---- GEMM3: O_h = P @ V (P rows wave-private; vT from B2) ----
        bf16x8 ap0 = (myrow < 49) ? ldfrag(&p_s[myrow * 72 +  0 + lg * 8]) : zfrag();
        bf16x8 ap1 = (myrow < 49) ? ldfrag(&p_s[myrow * 72 + 32 + lg * 8]) : zfrag();
        #pragma unroll
        for (int nt = 0; nt < 2; ++nt) {
            f32x4 c = {0.f, 0.f, 0.f, 0.f};
            c = mfma16(ap0, ldfrag(&vT_s[(nt * 16 + lr) * 72 +  0 + lg * 8]), c);
            c = mfma16(ap1, ldfrag(&vT_s[(nt * 16 + lr) * 72 + 32 + lg * 8]), c);
            #pragma unroll
            for (int reg = 0; reg < 4; ++reg) {
                int r = 16 * w + lg * 4 + reg;
                if (r < 49) o_s[r * 40 + nt * 16 + lr] = f2bu(c[reg]);
            }
        }

        // ---- GEMM4: proj += O_h @ Wout_h (o rows wave-private) ----
        bf16x8 ao = (myrow < 49) ? ldfrag(&o_s[myrow * 40 + lg * 8]) : zfrag();
        #pragma unroll
        for (int nt = 0; nt < 6; ++nt) {
            const u16* wb = wso + ((size_t)(h * 6 + nt) * 64 + l) * 8;
            proj[nt] = mfma16(ao, ldfrag(wb), proj[nt]);
        }
    }

    // ---- epilogue: +b_out, write out (rolled back), fused col sum/max ----
    float csum[6], cmax[6];
    #pragma unroll
    for (int nt = 0; nt < 6; ++nt) { csum[nt] = 0.f; cmax[nt] = -1e30f; }
    #pragma unroll
    for (int nt = 0; nt < 6; ++nt) {
        int c = nt * 16 + lr;
        float bo = b_out[c];
        #pragma unroll
        for (int reg = 0; reg < 4; ++reg) {
            int tok = 16 * w + lg * 4 + reg;
            if (tok < 49) {
                float v = proj[nt][reg] + bo;
                int sr = wh * 7 + tok / 7 + 3;  if (sr >= 224) sr -= 224;
                int sc = ww * 7 + tok % 7 + 3;  if (sc >= 224) sc -= 224;
                out[(((size_t)b * 224 + sr) * 224 + sc) * 96 + c] = v;
                csum[nt] += v;
                cmax[nt] = fmaxf(cmax[nt], v);
            }
        }
    }
    #pragma unroll
    for (int nt = 0; nt < 6; ++nt) {        // reduce over the wave's 16 rows
        csum[nt] += __shfl_xor(csum[nt], 16);
        csum[nt] += __shfl_xor(csum[nt], 32);
        cmax[nt] = fmaxf(cmax[nt], __shfl_xor(cmax[nt], 16));
        cmax[nt] = fmaxf(cmax[nt], __shfl_xor(cmax[nt], 32));
    }
    if (lg == 0) {
        #pragma unroll
        for (int nt = 0; nt < 6; ++nt) {
            rsum[w * 96 + nt * 16 + lr] = csum[nt];
            rmax[w * 96 + nt * 16 + lr] = cmax[nt];
        }
    }
    __syncthreads();
    if (tid < 96) {
        size_t o = ((size_t)b * 1024 + win) * 96 + tid;
        psum_win[o] = rsum[tid] + rsum[96 + tid] + rsum[192 + tid] + rsum[288 + tid];
        pmax_win[o] = fmaxf(fmaxf(rmax[tid], rmax[96 + tid]),
                            fmaxf(rmax[192 + tid], rmax[288 + tid]));
    }
}

// ============================================================================
// Gate: reduce 1024 per-window partials -> avg/max -> two MLPs -> sigmoid.
// One block per batch, 384 threads (4 subs x 96 channels).
// ============================================================================
__global__ __launch_bounds__(384) void gate_kernel(
    const float* __restrict__ psum, const float* __restrict__ pmax,
    const float* __restrict__ w11, const float* __restrict__ b11,
    const float* __restrict__ w12, const float* __restrict__ b12,
    const float* __restrict__ w21, const float* __restrict__ b21,
    const float* __restrict__ w22, const float* __restrict__ b22,
    float* __restrict__ gate)
{
    const int b = blockIdx.x;
    const int tid = threadIdx.x;
    const int c = tid % 96, sub = tid / 96;
    __shared__ float ls[384], lm[384];
    __shared__ float avg[96], mx[96], h1[96], h2[96];

    float s = 0.f, m = -1e30f;
    for (int k = sub * 256; k < sub * 256 + 256; ++k) {
        size_t o = ((size_t)b * 1024 + k) * 96 + c;
        s += psum[o];
        m = fmaxf(m, pmax[o]);
    }
    ls[tid] = s; lm[tid] = m;
    __syncthreads();
    if (tid < 96) {
        s = ls[c] + ls[96 + c] + ls[192 + c] + ls[288 + c];
        m = fmaxf(fmaxf(lm[c], lm[96 + c]), fmaxf(lm[192 + c], lm[288 + c]));
        avg[c] = s * (1.0f / 50176.0f);
        mx[c]  = m;
    }
    __syncthreads();
    if (tid < 96) {
        float sa = b11[c], sm = b21[c];
        for (int ic = 0; ic < 96; ++ic) {
            sa = fmaf(avg[ic], w11[ic * 96 + c], sa);
            sm = fmaf(mx[ic],  w21[ic * 96 + c], sm);
        }
        h1[c] = fmaxf(sa, 0.f);
        h2[c] = fmaxf(sm, 0.f);
    }
    __syncthreads();
    if (tid < 96) {
        float a = b12[c], m2 = b22[c];
        for (int hh = 0; hh < 96; ++hh) {
            a  = fmaf(h1[hh], w12[hh * 96 + c], a);
            m2 = fmaf(h2[hh], w22[hh * 96 + c], m2);
        }
        float g = a + m2;
        gate[b * 96 + c] = 1.0f / (1.0f + __expf(-g));
    }
}

// ============================================================================
// Final: out *= gate[b,c] (in place, float4)
// ============================================================================
__global__ __launch_bounds__(256) void scale_kernel(
    float* __restrict__ out, const float* __restrict__ gate)
{
    const size_t total4 = 38535168u / 4;
    for (size_t i4 = (size_t)blockIdx.x * blockDim.x + threadIdx.x; i4 < total4;
         i4 += (size_t)gridDim.x * blockDim.x) {
        size_t base = i4 * 4;
        int c = (int)(base % 96);
        int b = (int)(base / ((size_t)50176 * 96));
        float4 u = ((const float4*)out)[i4];
        float4 g = *(const float4*)(gate + b * 96 + c);
        float4 o;
        o.x = u.x * g.x; o.y = u.y * g.y; o.z = u.z * g.z; o.w = u.w * g.w;
        ((float4*)out)[i4] = o;
    }
}

extern "C" void kernel_launch(void* const* d_in, const int* in_sizes, int n_in,
                              void* d_out, int out_size, void* d_ws, size_t ws_size,
                              hipStream_t stream) {
    const float* x     = (const float*)d_in[0];
    const float* wqkv  = (const float*)d_in[1];
    const float* pos   = (const float*)d_in[2];
    const float* wout  = (const float*)d_in[3];
    const float* bout  = (const float*)d_in[4];
    const float* m1w1  = (const float*)d_in[5];
    const float* m1b1  = (const float*)d_in[6];
    const float* m1w2  = (const float*)d_in[7];
    const float* m1b2  = (const float*)d_in[8];
    const float* m2w1  = (const float*)d_in[9];
    const float* m2b1  = (const float*)d_in[10];
    const float* m2w2  = (const float*)d_in[11];
    const float* m2b2  = (const float*)d_in[12];
    float* out = (float*)d_out;

    float* psum_win = (float*)d_ws;             // 8*1024*96 f32
    float* pmax_win = psum_win + 8 * 1024 * 96; // 8*1024*96 f32
    float* gatep    = pmax_win + 8 * 1024 * 96; // 8*96 f32
    u16*   wsq      = (u16*)(gatep + 8 * 96);   // 27648 bf16
    u16*   wso      = wsq + 27648;              // 9216 bf16

    hipLaunchKernelGGL(prep_weights, dim3(108), dim3(256), 0, stream,
                       wqkv, wout, wsq, wso);
    hipLaunchKernelGGL(swin_attn_mfma, dim3(8192), dim3(256), 0, stream,
                       x, pos, wsq, wso, bout, out, psum_win, pmax_win);
    hipLaunchKernelGGL(gate_kernel, dim3(8), dim3(384), 0, stream,
                       psum_win, pmax_win, m1w1, m1b1, m1w2, m1b2,
                       m2w1, m2b1, m2w2, m2b2, gatep);
    hipLaunchKernelGGL(scale_kernel, dim3(2048), dim3(256), 0, stream,
                       out, gatep);
}

// Round 6
// 249.638 us; speedup vs baseline: 6.9211x; 1.2439x over previous
//
#include <hip/hip_runtime.h>
#include <hip/hip_bf16.h>

typedef __attribute__((ext_vector_type(8))) __bf16 bf16x8;
typedef __attribute__((ext_vector_type(4))) float f32x4;
typedef unsigned short u16;
typedef unsigned long long u64;

#define SCALE_QK 0.17677669529663687f  // 32^-0.5

static __device__ __forceinline__ u16 f2b(float f) {
    union { __bf16 h; u16 u; } z; z.h = (__bf16)f; return z.u;
}
static __device__ __forceinline__ float bu2f(u16 s) {
    union { unsigned u; float f; } z; z.u = ((unsigned)s) << 16; return z.f;
}
static __device__ __forceinline__ f32x4 mfma16(bf16x8 a, bf16x8 b, f32x4 c) {
    return __builtin_amdgcn_mfma_f32_16x16x32_bf16(a, b, c, 0, 0, 0);
}
static __device__ __forceinline__ bf16x8 ldfrag(const u16* p) {
    return *(const bf16x8*)p;
}
// pack 4 floats -> 4 bf16 in one u64 (compiler emits v_cvt_pk_bf16_f32 x2)
static __device__ __forceinline__ u64 pack4(float a, float b, float c, float d) {
    union { __bf16 h[4]; u64 q; } z;
    z.h[0] = (__bf16)a; z.h[1] = (__bf16)b; z.h[2] = (__bf16)c; z.h[3] = (__bf16)d;
    return z.q;
}
static __device__ __forceinline__ bf16x8 pack8(float4 a, float4 b) {
    union { __bf16 h[8]; bf16x8 v; } z;
    z.h[0] = (__bf16)a.x; z.h[1] = (__bf16)a.y; z.h[2] = (__bf16)a.z; z.h[3] = (__bf16)a.w;
    z.h[4] = (__bf16)b.x; z.h[5] = (__bf16)b.y; z.h[6] = (__bf16)b.z; z.h[7] = (__bf16)b.w;
    return z.v;
}

// ============================================================================
// Prep: swizzle w_qkv / w_out into MFMA fragment order (bf16) in workspace.
// Lane-map for A(row r, k) and B(col n, k) fragments is identical, so the
// same table serves Q/K (used as A of the swapped GEMM) and V (used as B).
// ============================================================================
__global__ __launch_bounds__(256) void prep_weights(
    const float* __restrict__ w_qkv, const float* __restrict__ w_out,
    u16* __restrict__ wsq, u16* __restrict__ wso)
{
    int idx = blockIdx.x * 256 + threadIdx.x;
    if (idx < 27648) {
        int e = idx & 7, lA = (idx >> 3) & 63;
        int rest = idx >> 9;              // h*18 + sec*3 + ks
        int ks = rest % 3, sec = (rest / 3) % 6, h = rest / 18;
        int krow = ks * 32 + (lA >> 4) * 8 + e;
        int n = lA & 15;
        int gcol;
        if (sec < 2)      gcol = h * 32 + sec * 16 + n;              // Q
        else if (sec < 4) gcol = 96 + h * 32 + (sec - 2) * 16 + n;   // K
        else              gcol = 192 + h * 32 + (sec - 4) * 16 + n;  // V
        wsq[idx] = f2b(w_qkv[krow * 288 + gcol]);
    }
    if (idx < 9216) {
        int e = idx & 7, lA = (idx >> 3) & 63;
        int rest = idx >> 9;              // h*6 + nt
        int nt = rest % 6, h = rest / 6;
        int krow = h * 32 + (lA >> 4) * 8 + e;
        wso[idx] = f2b(w_out[krow * 96 + nt * 16 + (lA & 15)]);
    }
}

// ============================================================================
// Fused MFMA swin block, swapped-operand edition.
// One block per (batch, window); 4 waves; wave w owns tokens 16w..16w+15.
// All LDS stores are packed 8B; softmax needs only 2 shfl_xor; no row guards
// (bias -1e30 exactly zeroes invalid j columns; invalid i rows discarded).
// LDS ~27 KB. 2 barriers per head (K, V^T are the only cross-wave arrays).
// ============================================================================
__global__ __launch_bounds__(256, 4) void swin_attn_mfma(
    const float* __restrict__ x,
    const float* __restrict__ pos_emb,
    const u16*  __restrict__ wsq,
    const u16*  __restrict__ wso,
    const float* __restrict__ b_out,
    float* __restrict__ outf,        // f32 fallback (may be null)
    u16*  __restrict__ outw,         // bf16 intermediate (may be null)
    float* __restrict__ psum_win,    // [8*1024][96]
    float* __restrict__ pmax_win,    // [8*1024][96]
    int write_bf16)
{
    __shared__ __attribute__((aligned(16))) u16 qo_s[64 * 40];  // Q then O (wave-private rows)
    __shared__ __attribute__((aligned(16))) u16 k_s[64 * 40];   // K  [token][d]
    __shared__ __attribute__((aligned(16))) u16 p_s[64 * 72];   // P  [i][j] (unnormalized)
    __shared__ __attribute__((aligned(16))) u16 vT_s[32 * 72];  // V^T [d][token]
    __shared__ float rsum[4 * 96];
    __shared__ float rmax[4 * 96];

    const int blk = blockIdx.x;
    const int b = blk >> 10, win = blk & 1023;
    const int wh = win >> 5, ww = win & 31;
    const int tid = threadIdx.x;
    const int w = tid >> 6, l = tid & 63, lr = l & 15, lg = l >> 4;
    const int myrow = 16 * w + lr;        // this lane's token (X/Q/P/O row, S^T col)

    // ---- X fragments direct from global (dual-use as A- or B-operand) ----
    // rows 49..63 read wrapped (valid) data; results are masked/discarded.
    bf16x8 ax0, ax1, ax2;
    {
        int sr = wh * 7 + myrow / 7 + 3;  if (sr >= 224) sr -= 224;
        int sc = ww * 7 + myrow % 7 + 3;  if (sc >= 224) sc -= 224;
        const float* xr = x + (((size_t)b * 224 + sr) * 224 + sc) * 96 + lg * 8;
        ax0 = pack8(*(const float4*)(xr +  0), *(const float4*)(xr +  4));
        ax1 = pack8(*(const float4*)(xr + 32), *(const float4*)(xr + 36));
        ax2 = pack8(*(const float4*)(xr + 64), *(const float4*)(xr + 68));
    }

    // ---- per-lane bias/mask: S^T element (j = jt*16+lg*4+reg, i = myrow) ----
    float bias[4][4];
    {
        const bool mUL = (wh == 31), mLR = (ww == 31);
        const int i = myrow;
        const int ir = i / 7, ic = i - ir * 7;
        #pragma unroll
        for (int jt = 0; jt < 4; ++jt) {
            #pragma unroll
            for (int reg = 0; reg < 4; ++reg) {
                int j = jt * 16 + lg * 4 + reg;
                float v;
                if (j >= 49) v = -1e30f;          // kills invalid j exactly (exp->0)
                else if (i >= 49) v = 0.f;        // keep finite; row discarded later
                else {
                    int jr = j / 7, jc = j - jr * 7;
                    v = pos_emb[(jr - ir + 6) * 13 + (jc - ic + 6)];
                    if (mUL && ((ir >= 4) != (jr >= 4))) v = -1e30f;
                    if (mLR && ((ic >= 4) != (jc >= 4))) v = -1e30f;
                }
                bias[jt][reg] = v;
            }
        }
    }

    f32x4 proj[6];
    #pragma unroll
    for (int nt = 0; nt < 6; ++nt) proj[nt] = (f32x4){0.f, 0.f, 0.f, 0.f};

    for (int h = 0; h < 3; ++h) {
        if (h) __syncthreads();   // B1: prev head's K/vT reads all done

        // ---- GEMM1: Q^T,K^T (swapped: A=W-frag, B=X-frag) and V^T ----
        #pragma unroll
        for (int sec = 0; sec < 6; ++sec) {
            const u16* wb = wsq + ((size_t)(h * 6 + sec) * 3 * 64 + l) * 8;
            f32x4 c = {0.f, 0.f, 0.f, 0.f};
            if (sec < 4) {        // Q/K swapped: C col = token(lr), row = d
                c = mfma16(ldfrag(wb), ax0, c);
                c = mfma16(ldfrag(wb + 512), ax1, c);
                c = mfma16(ldfrag(wb + 1024), ax2, c);
                u64 pk = pack4(c[0], c[1], c[2], c[3]);   // 4 consecutive d
                if (sec < 2)
                    *(u64*)&qo_s[myrow * 40 + (sec & 1) * 16 + lg * 4] = pk;
                else
                    *(u64*)&k_s[myrow * 40 + (sec & 1) * 16 + lg * 4] = pk;
            } else {              // V unswapped: C col = d(lr), row = token
                c = mfma16(ax0, ldfrag(wb), c);
                c = mfma16(ax1, ldfrag(wb + 512), c);
                c = mfma16(ax2, ldfrag(wb + 1024), c);
                u64 pk = pack4(c[0], c[1], c[2], c[3]);   // 4 consecutive tokens
                *(u64*)&vT_s[((sec - 4) * 16 + lr) * 72 + 16 * w + lg * 4] = pk;
            }
        }
        __syncthreads();   // B2: K, V^T visible to all waves

        // ---- GEMM2: S^T = K @ Q^T  (A=K rows j, B=own Q cols i; k=d=32) ----
        bf16x8 bq = ldfrag(&qo_s[myrow * 40 + lg * 8]);
        f32x4 S[4];
        #pragma unroll
        for (int jt = 0; jt < 4; ++jt) {
            f32x4 z = {0.f, 0.f, 0.f, 0.f};
            S[jt] = mfma16(ldfrag(&k_s[(jt * 16 + lr) * 40 + lg * 8]), bq, z);
        }

        // ---- softmax: lane holds 16 j-entries of query i=myrow ----
        float ssum = 0.f;
        float e[4][4];
        #pragma unroll
        for (int jt = 0; jt < 4; ++jt) {
            #pragma unroll
            for (int reg = 0; reg < 4; ++reg) {
                float v = __expf(fmaf(S[jt][reg], SCALE_QK, bias[jt][reg]));
                e[jt][reg] = v; ssum += v;
            }
        }
        ssum += __shfl_xor(ssum, 16);
        ssum += __shfl_xor(ssum, 32);
        float inv = 1.f / ssum;
        #pragma unroll
        for (int jt = 0; jt < 4; ++jt)
            *(u64*)&p_s[myrow * 72 + jt * 16 + lg * 4] =
                pack4(e[jt][0], e[jt][1], e[jt][2], e[jt][3]);

        // ---- GEMM3: O^T = V^T @ P^T (A=V rows d, B=own P cols i; k=j=64) ----
        bf16x8 bp0 = ldfrag(&p_s[myrow * 72 +  0 + lg * 8]);
        bf16x8 bp1 = ldfrag(&p_s[myrow * 72 + 32 + lg * 8]);
        #pragma unroll
        for (int mt = 0; mt < 2; ++mt) {
            f32x4 c = {0.f, 0.f, 0.f, 0.f};
            c = mfma16(ldfrag(&vT_s[(mt * 16 + lr) * 72 +  0 + lg * 8]), bp0, c);
            c = mfma16(ldfrag(&vT_s[(mt * 16 + lr) * 72 + 32 + lg * 8]), bp1, c);
            // deferred softmax normalization: this lane's col i == myrow
            *(u64*)&qo_s[myrow * 40 + mt * 16 + lg * 4] =
                pack4(c[0] * inv, c[1] * inv, c[2] * inv, c[3] * inv);
        }

        // ---- GEMM4: proj += O @ Wout_h (A=own O rows, k=d=32) ----
        bf16x8 ao = ldfrag(&qo_s[myrow * 40 + lg * 8]);
        #pragma unroll
        for (int nt = 0; nt < 6; ++nt) {
            const u16* wb = wso + ((size_t)(h * 6 + nt) * 64 + l) * 8;
            proj[nt] = mfma16(ao, ldfrag(wb), proj[nt]);
        }
    }

    // ---- epilogue: +b_out, write out (rolled back), fused col sum/max ----
    float csum[6], cmax[6];
    #pragma unroll
    for (int nt = 0; nt < 6; ++nt) { csum[nt] = 0.f; cmax[nt] = -1e30f; }
    #pragma unroll
    for (int nt = 0; nt < 6; ++nt) {
        int c = nt * 16 + lr;
        float bo = b_out[c];
        #pragma unroll
        for (int reg = 0; reg < 4; ++reg) {
            int tok = 16 * w + lg * 4 + reg;
            if (tok < 49) {
                float v = proj[nt][reg] + bo;
                int sr = wh * 7 + tok / 7 + 3;  if (sr >= 224) sr -= 224;
                int sc = ww * 7 + tok % 7 + 3;  if (sc >= 224) sc -= 224;
                size_t o = (((size_t)b * 224 + sr) * 224 + sc) * 96 + c;
                if (write_bf16) outw[o] = f2b(v);
                else            outf[o] = v;
                csum[nt] += v;
                cmax[nt] = fmaxf(cmax[nt], v);
            }
        }
    }
    #pragma unroll
    for (int nt = 0; nt < 6; ++nt) {
        csum[nt] += __shfl_xor(csum[nt], 16);
        csum[nt] += __shfl_xor(csum[nt], 32);
        cmax[nt] = fmaxf(cmax[nt], __shfl_xor(cmax[nt], 16));
        cmax[nt] = fmaxf(cmax[nt], __shfl_xor(cmax[nt], 32));
    }
    if (lg == 0) {
        #pragma unroll
        for (int nt = 0; nt < 6; ++nt) {
            rsum[w * 96 + nt * 16 + lr] = csum[nt];
            rmax[w * 96 + nt * 16 + lr] = cmax[nt];
        }
    }
    __syncthreads();
    if (tid < 96) {
        size_t o = ((size_t)b * 1024 + win) * 96 + tid;
        psum_win[o] = rsum[tid] + rsum[96 + tid] + rsum[192 + tid] + rsum[288 + tid];
        pmax_win[o] = fmaxf(fmaxf(rmax[tid], rmax[96 + tid]),
                            fmaxf(rmax[192 + tid], rmax[288 + tid]));
    }
}

// ============================================================================
// Gate: reduce 1024 per-window partials -> avg/max -> two MLPs -> sigmoid.
// ============================================================================
__global__ __launch_bounds__(384) void gate_kernel(
    const float* __restrict__ psum, const float* __restrict__ pmax,
    const float* __restrict__ w11, const float* __restrict__ b11,
    const float* __restrict__ w12, const float* __restrict__ b12,
    const float* __restrict__ w21, const float* __restrict__ b21,
    const float* __restrict__ w22, const float* __restrict__ b22,
    float* __restrict__ gate)
{
    const int b = blockIdx.x;
    const int tid = threadIdx.x;
    const int c = tid % 96, sub = tid / 96;
    __shared__ float ls[384], lm[384];
    __shared__ float avg[96], mx[96], h1[96], h2[96];

    float s = 0.f, m = -1e30f;
    for (int k = sub * 256; k < sub * 256 + 256; ++k) {
        size_t o = ((size_t)b * 1024 + k) * 96 + c;
        s += psum[o];
        m = fmaxf(m, pmax[o]);
    }
    ls[tid] = s; lm[tid] = m;
    __syncthreads();
    if (tid < 96) {
        s = ls[c] + ls[96 + c] + ls[192 + c] + ls[288 + c];
        m = fmaxf(fmaxf(lm[c], lm[96 + c]), fmaxf(lm[192 + c], lm[288 + c]));
        avg[c] = s * (1.0f / 50176.0f);
        mx[c]  = m;
    }
    __syncthreads();
    if (tid < 96) {
        float sa = b11[c], sm = b21[c];
        for (int ic = 0; ic < 96; ++ic) {
            sa = fmaf(avg[ic], w11[ic * 96 + c], sa);
            sm = fmaf(mx[ic],  w21[ic * 96 + c], sm);
        }
        h1[c] = fmaxf(sa, 0.f);
        h2[c] = fmaxf(sm, 0.f);
    }
    __syncthreads();
    if (tid < 96) {
        float a = b12[c], m2 = b22[c];
        for (int hh = 0; hh < 96; ++hh) {
            a  = fmaf(h1[hh], w12[hh * 96 + c], a);
            m2 = fmaf(h2[hh], w22[hh * 96 + c], m2);
        }
        float g = a + m2;
        gate[b * 96 + c] = 1.0f / (1.0f + __expf(-g));
    }
}

// ============================================================================
// Final scale: out_f32 = bf16_ws * gate  (bf16 intermediate path)
// ============================================================================
__global__ __launch_bounds__(256) void scale_bf16_kernel(
    const u16* __restrict__ outw, float* __restrict__ out,
    const float* __restrict__ gate)
{
    const size_t total8 = 38535168u / 8;   // 4,816,896
    for (size_t i8 = (size_t)blockIdx.x * blockDim.x + threadIdx.x; i8 < total8;
         i8 += (size_t)gridDim.x * blockDim.x) {
        size_t base = i8 * 8;
        int c = (int)(base % 96);
        int b = (int)(base / ((size_t)50176 * 96));
        u64 pk0 = *(const u64*)(outw + base);
        u64 pk1 = *(const u64*)(outw + base + 4);
        float4 g0 = *(const float4*)(gate + b * 96 + c);
        float4 g1 = *(const float4*)(gate + b * 96 + c + 4);
        float4 o0, o1;
        o0.x = bu2f((u16)(pk0      )) * g0.x;
        o0.y = bu2f((u16)(pk0 >> 16)) * g0.y;
        o0.z = bu2f((u16)(pk0 >> 32)) * g0.z;
        o0.w = bu2f((u16)(pk0 >> 48)) * g0.w;
        o1.x = bu2f((u16)(pk1      )) * g1.x;
        o1.y = bu2f((u16)(pk1 >> 16)) * g1.y;
        o1.z = bu2f((u16)(pk1 >> 32)) * g1.z;
        o1.w = bu2f((u16)(pk1 >> 48)) * g1.w;
        *(float4*)(out + base)     = o0;
        *(float4*)(out + base + 4) = o1;
    }
}

// f32 in-place fallback
__global__ __launch_bounds__(256) void scale_f32_kernel(
    float* __restrict__ out, const float* __restrict__ gate)
{
    const size_t total4 = 38535168u / 4;
    for (size_t i4 = (size_t)blockIdx.x * blockDim.x + threadIdx.x; i4 < total4;
         i4 += (size_t)gridDim.x * blockDim.x) {
        size_t base = i4 * 4;
        int c = (int)(base % 96);
        int b = (int)(base / ((size_t)50176 * 96));
        float4 u = ((const float4*)out)[i4];
        float4 g = *(const float4*)(gate + b * 96 + c);
        float4 o;
        o.x = u.x * g.x; o.y = u.y * g.y; o.z = u.z * g.z; o.w = u.w * g.w;
        ((float4*)out)[i4] = o;
    }
}

extern "C" void kernel_launch(void* const* d_in, const int* in_sizes, int n_in,
                              void* d_out, int out_size, void* d_ws, size_t ws_size,
                              hipStream_t stream) {
    const float* x     = (const float*)d_in[0];
    const float* wqkv  = (const float*)d_in[1];
    const float* pos   = (const float*)d_in[2];
    const float* wout  = (const float*)d_in[3];
    const float* bout  = (const float*)d_in[4];
    const float* m1w1  = (const float*)d_in[5];
    const float* m1b1  = (const float*)d_in[6];
    const float* m1w2  = (const float*)d_in[7];
    const float* m1b2  = (const float*)d_in[8];
    const float* m2w1  = (const float*)d_in[9];
    const float* m2b1  = (const float*)d_in[10];
    const float* m2w2  = (const float*)d_in[11];
    const float* m2b2  = (const float*)d_in[12];
    float* out = (float*)d_out;

    float* psum_win = (float*)d_ws;             // 8*1024*96 f32 = 3.15 MB
    float* pmax_win = psum_win + 8 * 1024 * 96; // 3.15 MB
    float* gatep    = pmax_win + 8 * 1024 * 96; // 3 KB
    u16*   wsq      = (u16*)(gatep + 8 * 96);   // 55 KB
    u16*   wso      = wsq + 27648;              // 18 KB
    u16*   outw     = wso + 9216;               // 77.1 MB (bf16 intermediate)

    const size_t base_bytes = (size_t)((char*)outw - (char*)d_ws);
    const size_t outw_bytes = (size_t)8 * 50176 * 96 * sizeof(u16);
    const int use_bf16 = (ws_size >= base_bytes + outw_bytes) ? 1 : 0;

    hipLaunchKernelGGL(prep_weights, dim3(108), dim3(256), 0, stream,
                       wqkv, wout, wsq, wso);
    hipLaunchKernelGGL(swin_attn_mfma, dim3(8192), dim3(256), 0, stream,
                       x, pos, wsq, wso, bout,
                       use_bf16 ? nullptr : out, use_bf16 ? outw : nullptr,
                       psum_win, pmax_win, use_bf16);
    hipLaunchKernelGGL(gate_kernel, dim3(8), dim3(384), 0, stream,
                       psum_win, pmax_win, m1w1, m1b1, m1w2, m1b2,
                       m2w1, m2b1, m2w2, m2b2, gatep);
    if (use_bf16) {
        hipLaunchKernelGGL(scale_bf16_kernel, dim3(2048), dim3(256), 0, stream,
                           outw, out, gatep);
    } else {
        hipLaunchKernelGGL(scale_f32_kernel, dim3(2048), dim3(256), 0, stream,
                           out, gatep);
    }
}